// Round 2
// baseline (337.838 us; speedup 1.0000x reference)
//
#include <hip/hip_runtime.h>
#include <hip/hip_bf16.h>
#include <hip/hip_fp16.h>

#define BB 32
#define TT 256
#define MM 16
#define DD 128
#define HH 128

typedef unsigned int uint;
typedef unsigned short ushort;

__device__ __forceinline__ float bl16(uint u){ return __uint_as_float(u << 16); }
__device__ __forceinline__ float bh16(uint u){ return __uint_as_float(u & 0xffff0000u); }

__device__ __forceinline__ float hsig(float x){
  // clamp(0.2x+0.5, 0, 1) via v_med3_f32
  return __builtin_amdgcn_fmed3f(fmaf(x, 0.2f, 0.5f), 0.0f, 1.0f);
}
__device__ __forceinline__ float tanh_f(float x){
  return 1.0f - 2.0f / (__expf(2.0f * x) + 1.0f);   // saturates correctly
}

typedef _Float16 h2v __attribute__((ext_vector_type(2)));
__device__ __forceinline__ h2v u2hv(uint u){
  union{uint x; h2v h;} c; c.x = u; return c.h;
}

#if __has_builtin(__builtin_amdgcn_fdot2)
__device__ __forceinline__ float dot2(uint hu, uint uu, float c){
  return __builtin_amdgcn_fdot2(u2hv(hu), u2hv(uu), c, false);
}
#else
__device__ __forceinline__ float dot2(uint hu, uint uu, float c){
  h2v a = u2hv(hu), b = u2hv(uu);
  return fmaf((float)a.x, (float)b.x, fmaf((float)a.y, (float)b.y, c));
}
#endif

// quad_perm butterfly: all 4 quad lanes end with the quad sum
__device__ __forceinline__ float qsum4(float v){
  float t1 = __int_as_float(__builtin_amdgcn_mov_dpp(__float_as_int(v), 0xB1, 0xf, 0xf, true)); // [1,0,3,2]
  v += t1;
  float t2 = __int_as_float(__builtin_amdgcn_mov_dpp(__float_as_int(v), 0x4E, 0xf, 0xf, true)); // [2,3,0,1]
  return v + t2;
}

// 16 dot2s: one k/d-subtile (V = 4 f16-pairs) against all 4 gate matrices in RT.
// Index layout matches k_uprep packing: RT[g*16 + ss*4 + m].
#define DOT16(V, SS, A0, A1, A2, A3, RT) do{  \
  A0 = dot2((V).x, RT[ 0 + 4*(SS)], A0);      \
  A0 = dot2((V).y, RT[ 1 + 4*(SS)], A0);      \
  A0 = dot2((V).z, RT[ 2 + 4*(SS)], A0);      \
  A0 = dot2((V).w, RT[ 3 + 4*(SS)], A0);      \
  A1 = dot2((V).x, RT[16 + 4*(SS)], A1);      \
  A1 = dot2((V).y, RT[17 + 4*(SS)], A1);      \
  A1 = dot2((V).z, RT[18 + 4*(SS)], A1);      \
  A1 = dot2((V).w, RT[19 + 4*(SS)], A1);      \
  A2 = dot2((V).x, RT[32 + 4*(SS)], A2);      \
  A2 = dot2((V).y, RT[33 + 4*(SS)], A2);      \
  A2 = dot2((V).z, RT[34 + 4*(SS)], A2);      \
  A2 = dot2((V).w, RT[35 + 4*(SS)], A2);      \
  A3 = dot2((V).x, RT[48 + 4*(SS)], A3);      \
  A3 = dot2((V).y, RT[49 + 4*(SS)], A3);      \
  A3 = dot2((V).z, RT[50 + 4*(SS)], A3);      \
  A3 = dot2((V).w, RT[51 + 4*(SS)], A3);      \
}while(0)

// ---------------- K_init: dtype probe (flag=1 bf16, 0 fp32) + v_x[d] = sum_h W_a[d,h]
// (scores = con@W_a summed over cols; the h- and bias-parts are constant over m and
//  cancel in softmax, so only the first 128 rows of W_a matter.)
__global__ __launch_bounds__(128) void k_init(const void* __restrict__ xraw,
                                              const void* __restrict__ Wa,
                                              int* __restrict__ flag,
                                              float* __restrict__ vx){
  __shared__ int cnt[128];
  __shared__ int smode;
  int tid = threadIdx.x;
  const ushort* u = (const ushort*)xraw;
  int c = 0;
  for (int j = 0; j < 16; ++j){
    ushort v = u[2 * (tid * 16 + j)];
    float f = __uint_as_float(((uint)v) << 16);
    if (f == f && fabsf(f) < 64.f && fabsf(f) > 1e-12f) ++c;
  }
  cnt[tid] = c;
  __syncthreads();
  if (tid == 0){
    int s = 0;
    for (int j = 0; j < 128; ++j) s += cnt[j];
    int m = (s > 1024) ? 1 : 0;
    smode = m; *flag = m;
  }
  __syncthreads();
  int mode = smode;

  int d = tid;
  float s = 0.f;
  if (mode){
    const uint4* row = (const uint4*)((const ushort*)Wa + d * HH);
    #pragma unroll
    for (int q = 0; q < 16; ++q){
      uint4 v = row[q];
      s += bl16(v.x) + bh16(v.x) + bl16(v.y) + bh16(v.y)
         + bl16(v.z) + bh16(v.z) + bl16(v.w) + bh16(v.w);
    }
  } else {
    const float4* row = (const float4*)((const float*)Wa + d * HH);
    #pragma unroll
    for (int q = 0; q < 32; ++q){
      float4 v = row[q];
      s += v.x + v.y + v.z + v.w;
    }
  }
  vx[d] = s;
}

// ---------------- K_uprep: pack a [128,128] matrix quartet into per-thread f16 pairs.
// Dst flat idx = tid*64 + g*16 + ss*4 + m  (tid=(j<<2)|q). Each uint = half2 of
// (M[k][j], M[k+1][j]) with k = 32q + ((ss+q)&3)*8 + 2m  (bank rotation baked in).
// Used twice: {U_i,U_f,U_c,U_o}->Uw and {W_i,W_f,W_c,W_o}->Ww.
__global__ __launch_bounds__(256) void k_uprep(
  const void* __restrict__ M0, const void* __restrict__ M1,
  const void* __restrict__ M2, const void* __restrict__ M3,
  const int* __restrict__ flag, uint* __restrict__ dst)
{
  int mode = *flag;
  int idx = blockIdx.x * 256 + threadIdx.x;   // 0..32767
  int tid = idx >> 6;
  int rem = idx & 63;
  int g = rem >> 4, s = rem & 15;
  int ss = s >> 2, m = s & 3;
  int q = tid & 3, j = tid >> 2;
  int kr = (ss + q) & 3;
  int k = 32 * q + kr * 8 + 2 * m;
  const void* Ms[4] = {M0, M1, M2, M3};
  float ux, uy;
  if (mode){
    const ushort* U16 = (const ushort*)Ms[g];
    ux = __uint_as_float(((uint)U16[(size_t)k * HH + j]) << 16);
    uy = __uint_as_float(((uint)U16[(size_t)(k + 1) * HH + j]) << 16);
  } else {
    const float* U32 = (const float*)Ms[g];
    ux = U32[(size_t)k * HH + j];
    uy = U32[(size_t)(k + 1) * HH + j];
  }
  __half2 hv = __floats2half2_rn(ux, uy);
  union{__half2 h; uint x;} cv; cv.h = hv;
  dst[idx] = cv.x;
}

// ---------------- K1: softmax-pool, 2 (b,t)-tiles per block. Emits f16 now ---------
__global__ __launch_bounds__(256) void k_pool(const void* __restrict__ xraw,
                                              const int* __restrict__ flag,
                                              const float* __restrict__ vx,
                                              __half* __restrict__ newx){
  __shared__ float xs[2][MM][DD];   // 16 KB
  __shared__ float vxs[DD];
  __shared__ float part[2][128];
  __shared__ float sc[2][MM];
  int mode = *flag;
  int tid = threadIdx.x;
  int half = tid >> 7, t2 = tid & 127;
  int bt = blockIdx.x * 2 + half;       // tile 0..8191
  int b = bt >> 8, t = bt & 255;

  float* xdst = &xs[half][0][0];        // 2048 floats per tile
  if (mode){
    const uint4* s = (const uint4*)((const ushort*)xraw + (size_t)bt * 2048);
    #pragma unroll
    for (int q = 0; q < 2; ++q){
      int ch = t2 + 128 * q;
      uint4 v = s[ch];
      float* d = &xdst[ch * 8];
      d[0] = bl16(v.x); d[1] = bh16(v.x);
      d[2] = bl16(v.y); d[3] = bh16(v.y);
      d[4] = bl16(v.z); d[5] = bh16(v.z);
      d[6] = bl16(v.w); d[7] = bh16(v.w);
    }
  } else {
    const float4* s = (const float4*)((const float*)xraw + (size_t)bt * 2048);
    #pragma unroll
    for (int q = 0; q < 4; ++q){
      int ch = t2 + 128 * q;
      *(float4*)&xdst[ch * 4] = s[ch];
    }
  }
  if (tid < DD) vxs[tid] = vx[tid];
  __syncthreads();

  int m = t2 >> 3, cc = t2 & 7;
  float p = 0.f;
  #pragma unroll
  for (int j = 0; j < 16; ++j)
    p = fmaf(xs[half][m][cc * 16 + j], vxs[cc * 16 + j], p);
  part[half][t2] = p;
  __syncthreads();
  if (t2 < MM){
    float s = 0.f;
    #pragma unroll
    for (int q = 0; q < 8; ++q) s += part[half][t2 * 8 + q];
    sc[half][t2] = s;
  }
  __syncthreads();

  float mx = sc[half][0];
  #pragma unroll
  for (int m2 = 1; m2 < MM; ++m2) mx = fmaxf(mx, sc[half][m2]);
  float wgt[MM]; float den = 0.f;
  #pragma unroll
  for (int m2 = 0; m2 < MM; ++m2){ wgt[m2] = __expf(sc[half][m2] - mx); den += wgt[m2]; }
  float inv = 1.0f / den;

  float acc = 0.f;
  #pragma unroll
  for (int m2 = 0; m2 < MM; ++m2)
    acc = fmaf(wgt[m2], xs[half][m2][t2], acc);
  newx[((size_t)t * BB + b) * DD + t2] = __float2half(acc * inv);
}

// ---------------- K3: fused recurrence ----------------------------------------------
// R12: k_xproj FUSED in. Rationale: R11 showed k_rec is lockstep-latency-bound (8
// barrier-synced waves stall together on h ds_read latency + gate dep chains; -15%
// instr count gave 0%). The x-projection new_x@W_g+b_g has NO h dependence, so its
// 64 dot2/thread/step are scheduler-fillable into those bubbles:
//   - new_x (f16) staged once into 64 KB LDS; W packed like U into Wr[64] regs.
//   - per-quad d-quarter x-partials share the accumulator with h-partials; one
//     qsum4 reduces both; bias added after. The old m_q*xp mask trick + the global
//     Xp prefetch (and the whole 16 MB Xp round-trip) are gone.
//   - x-dots split: ss0/ss1 pre-barrier (fills write-drain+barrier skew),
//     ss2/ss3 post-barrier (fills the h ds_read latency window).
__global__ __attribute__((amdgpu_waves_per_eu(2, 2))) __launch_bounds__(512)
void k_rec(const __half* __restrict__ nxg, const uint* __restrict__ Uw,
           const uint* __restrict__ Ww,
           const void* __restrict__ b0_, const void* __restrict__ b1_,
           const void* __restrict__ b2_, const void* __restrict__ b3_,
           const int* __restrict__ flag, float* __restrict__ out)
{
  __shared__ __align__(16) uint nxs[TT][64];     // 64 KB: new_x rows, f16 pairs
  __shared__ __align__(16) __half hlds[2][HH];   // 512 B
  int tid = threadIdx.x;
  int b   = blockIdx.x;
  int q   = tid & 3;                  // k/d-quarter
  int j   = tid >> 2;                 // output col 0..127
  int mode = *flag;

  // ---- stage new_x[t][b][:] rows into LDS (4096 uint4, coalesced 256B rows) ----
  {
    const uint4* src = (const uint4*)nxg;
    uint4* dst = (uint4*)&nxs[0][0];
    #pragma unroll
    for (int i = 0; i < 8; ++i){
      int fu = i * 512 + tid;              // uint4 index 0..4095
      int r = fu >> 4, col = fu & 15;
      dst[fu] = src[((size_t)r * BB + b) * 16 + col];
    }
  }

  // ---- U and W register tiles: flat [g*16 + ss*4 + m], 32 contiguous uint4 loads --
  uint Ur[64], Wr[64];
  {
    const uint4* Ut = (const uint4*)(Uw + (size_t)tid * 64);
    const uint4* Wt = (const uint4*)(Ww + (size_t)tid * 64);
    #pragma unroll
    for (int i = 0; i < 16; ++i){
      uint4 u = Ut[i];
      Ur[4*i+0] = u.x; Ur[4*i+1] = u.y; Ur[4*i+2] = u.z; Ur[4*i+3] = u.w;
      uint4 w = Wt[i];
      Wr[4*i+0] = w.x; Wr[4*i+1] = w.y; Wr[4*i+2] = w.z; Wr[4*i+3] = w.w;
    }
  }

  float bias0, bias1, bias2, bias3;
  if (mode){
    bias0 = __uint_as_float(((uint)((const ushort*)b0_)[j]) << 16);
    bias1 = __uint_as_float(((uint)((const ushort*)b1_)[j]) << 16);
    bias2 = __uint_as_float(((uint)((const ushort*)b2_)[j]) << 16);
    bias3 = __uint_as_float(((uint)((const ushort*)b3_)[j]) << 16);
  } else {
    bias0 = ((const float*)b0_)[j];
    bias1 = ((const float*)b1_)[j];
    bias2 = ((const float*)b2_)[j];
    bias3 = ((const float*)b3_)[j];
  }

  if (tid < 64) ((uint*)&hlds[0][0])[tid] = 0;   // zero h buffer 0 (128 f16)
  __syncthreads();                               // nxs + h0 ready (drains vmem too)

  // rotation constants: uint4 index within a 16-uint4 row = q*4 + (ss+q)&3
  const int i0 = q * 4 + ((0 + q) & 3);
  const int i1 = q * 4 + ((1 + q) & 3);
  const int i2 = q * 4 + ((2 + q) & 3);
  const int i3 = q * 4 + ((3 + q) & 3);

  // ---- preloop: xa(0) from nx row 0; h(0)=0 fragments ----
  float xa0 = 0.f, xa1 = 0.f, xa2 = 0.f, xa3 = 0.f;
  {
    const uint4* row = (const uint4*)&nxs[0][0];
    uint4 n0 = row[i0], n1 = row[i1], n2 = row[i2], n3 = row[i3];
    DOT16(n0, 0, xa0, xa1, xa2, xa3, Wr);
    DOT16(n1, 1, xa0, xa1, xa2, xa3, Wr);
    DOT16(n2, 2, xa0, xa1, xa2, xa3, Wr);
    DOT16(n3, 3, xa0, xa1, xa2, xa3, Wr);
  }
  uint4 h80, h81, h82, h83;
  {
    const uint4* hb = (const uint4*)&hlds[0][0];
    h80 = hb[i0]; h81 = hb[i1]; h82 = hb[i2]; h83 = hb[i3];
  }

  float cst = 0.f, vh = 0.f;
  for (int t = 0; t < TT; ++t){
    // h-dots accumulate on top of the x-partials (one shared reduction)
    float a0 = xa0, a1 = xa1, a2 = xa2, a3 = xa3;
    DOT16(h80, 0, a0, a1, a2, a3, Ur);
    DOT16(h81, 1, a0, a1, a2, a3, Ur);
    DOT16(h82, 2, a0, a1, a2, a3, Ur);
    DOT16(h83, 3, a0, a1, a2, a3, Ur);
    float p0 = qsum4(a0) + bias0;
    float p1 = qsum4(a1) + bias1;
    float p2 = qsum4(a2) + bias2;
    float p3 = qsum4(a3) + bias3;

    float ig = hsig(p0), fg = hsig(p1), og = hsig(p3);
    float gg = tanh_f(p2);
    cst = fmaf(fg, cst, ig * gg);
    vh  = og * tanh_f(cst);
    if (q == 0) hlds[(t + 1) & 1][j] = __float2half(vh);

    // ---- x-dots for step t+1: h-independent bubble filler ----
    int tn = (t + 1 < TT) ? (t + 1) : (TT - 1);   // last iter: dummy (unused)
    const uint4* row = (const uint4*)&nxs[tn][0];
    uint4 n0 = row[i0], n1 = row[i1], n2 = row[i2], n3 = row[i3];
    float y0 = 0.f, y1 = 0.f, y2 = 0.f, y3 = 0.f;
    DOT16(n0, 0, y0, y1, y2, y3, Wr);             // pre-barrier half
    DOT16(n1, 1, y0, y1, y2, y3, Wr);

    // non-draining barrier: LDS ops must land (lgkmcnt); no vmem in loop at all
    asm volatile("s_waitcnt lgkmcnt(0)" ::: "memory");
    __builtin_amdgcn_s_barrier();
    asm volatile("" ::: "memory");

    // post-barrier: issue h(t+1) reads, fill their latency with remaining x-dots
    const uint4* hb = (const uint4*)&hlds[(t + 1) & 1][0];
    h80 = hb[i0]; h81 = hb[i1]; h82 = hb[i2]; h83 = hb[i3];
    DOT16(n2, 2, y0, y1, y2, y3, Wr);
    DOT16(n3, 3, y0, y1, y2, y3, Wr);
    xa0 = y0; xa1 = y1; xa2 = y2; xa3 = y3;
  }

  if (q == 0) out[b * HH + j] = vh;
}

extern "C" void kernel_launch(void* const* d_in, const int* in_sizes, int n_in,
                              void* d_out, int out_size, void* d_ws, size_t ws_size,
                              hipStream_t stream) {
  (void)in_sizes; (void)n_in; (void)out_size; (void)ws_size;

  // ---- workspace layout (~2.3 MB) ----
  // [0,16)            flag
  // [16,528)          vx fp32[128]
  // [1024, +128KB)    Uw uint[32768]  (packed f16 U pairs)
  // [+, +128KB)       Ww uint[32768]  (packed f16 W pairs)
  // [+, +2MB)         newx f16[8192*128]
  char* ws = (char*)d_ws;
  int* flag = (int*)ws;
  float* vx = (float*)(ws + 16);
  uint* Uw = (uint*)(ws + 1024);
  uint* Ww = (uint*)(ws + 1024 + 131072);
  __half* newx = (__half*)(ws + 1024 + 2 * 131072);

  k_init<<<1, 128, 0, stream>>>(d_in[0], d_in[1], flag, vx);
  k_uprep<<<128, 256, 0, stream>>>(d_in[4], d_in[7], d_in[10], d_in[13], flag, Uw);  // U_i,U_f,U_c,U_o
  k_uprep<<<128, 256, 0, stream>>>(d_in[3], d_in[6], d_in[9],  d_in[12], flag, Ww);  // W_i,W_f,W_c,W_o
  k_pool<<<BB * TT / 2, 256, 0, stream>>>(d_in[0], flag, vx, newx);
  k_rec<<<BB, 512, 0, stream>>>(newx, Uw, Ww,
      d_in[5], d_in[8], d_in[11], d_in[14],    // b_i, b_f, b_c, b_o
      flag, (float*)d_out);
}

// Round 3
// 269.567 us; speedup vs baseline: 1.2533x; 1.2533x over previous
//
#include <hip/hip_runtime.h>
#include <hip/hip_bf16.h>
#include <hip/hip_fp16.h>

#define BB 32
#define TT 256
#define MM 16
#define DD 128
#define HH 128

typedef unsigned int uint;
typedef unsigned short ushort;

typedef _Float16 f16;
typedef _Float16 f16x8 __attribute__((ext_vector_type(8)));
typedef float f32x4 __attribute__((ext_vector_type(4)));

__device__ __forceinline__ float bl16(uint u){ return __uint_as_float(u << 16); }
__device__ __forceinline__ float bh16(uint u){ return __uint_as_float(u & 0xffff0000u); }

__device__ __forceinline__ ushort f2bu(float f){
  __hip_bfloat16 h = __float2bfloat16(f);
  return *(ushort*)&h;
}

__device__ __forceinline__ float hsig(float x){
  // clamp(0.2x+0.5, 0, 1) via v_med3_f32
  return __builtin_amdgcn_fmed3f(fmaf(x, 0.2f, 0.5f), 0.0f, 1.0f);
}
__device__ __forceinline__ float tanh_f(float x){
  return 1.0f - 2.0f / (__expf(2.0f * x) + 1.0f);   // saturates correctly
}

__device__ __forceinline__ uint packh2(float a, float b){
  __half2 hv = __floats2half2_rn(a, b);
  union{__half2 h; uint x;} cv; cv.h = hv; return cv.x;
}

// ---------------- K_init: dtype probe (flag=1 bf16, 0 fp32) + v_x[d] = sum_h W_a[d,h]
// (scores = con@W_a summed over cols; h- and bias-parts are constant over m and
//  cancel in softmax, so only the first 128 rows of W_a matter.)
__global__ __launch_bounds__(128) void k_init(const void* __restrict__ xraw,
                                              const void* __restrict__ Wa,
                                              int* __restrict__ flag,
                                              float* __restrict__ vx){
  __shared__ int cnt[128];
  __shared__ int smode;
  int tid = threadIdx.x;
  const ushort* u = (const ushort*)xraw;
  int c = 0;
  for (int j = 0; j < 16; ++j){
    ushort v = u[2 * (tid * 16 + j)];
    float f = __uint_as_float(((uint)v) << 16);
    if (f == f && fabsf(f) < 64.f && fabsf(f) > 1e-12f) ++c;
  }
  cnt[tid] = c;
  __syncthreads();
  if (tid == 0){
    int s = 0;
    for (int j = 0; j < 128; ++j) s += cnt[j];
    int m = (s > 1024) ? 1 : 0;
    smode = m; *flag = m;
  }
  __syncthreads();
  int mode = smode;

  int d = tid;
  float s = 0.f;
  if (mode){
    const uint4* row = (const uint4*)((const ushort*)Wa + d * HH);
    #pragma unroll
    for (int q = 0; q < 16; ++q){
      uint4 v = row[q];
      s += bl16(v.x) + bh16(v.x) + bl16(v.y) + bh16(v.y)
         + bl16(v.z) + bh16(v.z) + bl16(v.w) + bh16(v.w);
    }
  } else {
    const float4* row = (const float4*)((const float*)Wa + d * HH);
    #pragma unroll
    for (int q = 0; q < 32; ++q){
      float4 v = row[q];
      s += v.x + v.y + v.z + v.w;
    }
  }
  vx[d] = s;
}

// ---------------- K_uprep2: pack U quartet into MFMA B-fragments (f16) --------------
// Frag f = (g*4+kc)*8 + w covers gate g, k-chunk kc (K=32), col-block w (16 cols).
// Lane l, element e (0..7): B[k][c] with k = kc*32 + (l>>4)*8 + e, c = w*16 + (l&15).
// dst[f*64 + l] = uint4 of 8 f16 (pair-packed low-first). k_rec fills its A-frags
// with the SAME k<->(lane,elem) rule, so any common hardware k-permutation cancels.
__global__ __launch_bounds__(256) void k_uprep2(
  const void* __restrict__ M0, const void* __restrict__ M1,
  const void* __restrict__ M2, const void* __restrict__ M3,
  const int* __restrict__ flag, uint4* __restrict__ dst)
{
  int mode = *flag;
  int idx = blockIdx.x * 256 + threadIdx.x;   // 0..8191
  int f = idx >> 6, lane = idx & 63;
  int g = f >> 5, kc = (f >> 3) & 3, w = f & 7;
  int k0 = kc * 32 + (lane >> 4) * 8;
  int c  = w * 16 + (lane & 15);
  const void* Ms[4] = {M0, M1, M2, M3};
  float v[8];
  if (mode){
    const ushort* U = (const ushort*)Ms[g];
    #pragma unroll
    for (int e = 0; e < 8; ++e)
      v[e] = __uint_as_float(((uint)U[(size_t)(k0 + e) * HH + c]) << 16);
  } else {
    const float* U = (const float*)Ms[g];
    #pragma unroll
    for (int e = 0; e < 8; ++e)
      v[e] = U[(size_t)(k0 + e) * HH + c];
  }
  uint4 o;
  o.x = packh2(v[0], v[1]); o.y = packh2(v[2], v[3]);
  o.z = packh2(v[4], v[5]); o.w = packh2(v[6], v[7]);
  dst[idx] = o;
}

// ---------------- K1: softmax-pool, 2 (b,t)-tiles per block (bf16 out) --------------
__global__ __launch_bounds__(256) void k_pool(const void* __restrict__ xraw,
                                              const int* __restrict__ flag,
                                              const float* __restrict__ vx,
                                              __hip_bfloat16* __restrict__ newx){
  __shared__ float xs[2][MM][DD];   // 16 KB
  __shared__ float vxs[DD];
  __shared__ float part[2][128];
  __shared__ float sc[2][MM];
  int mode = *flag;
  int tid = threadIdx.x;
  int half = tid >> 7, t2 = tid & 127;
  int bt = blockIdx.x * 2 + half;       // tile 0..8191
  int b = bt >> 8, t = bt & 255;

  float* xdst = &xs[half][0][0];        // 2048 floats per tile
  if (mode){
    const uint4* s = (const uint4*)((const ushort*)xraw + (size_t)bt * 2048);
    #pragma unroll
    for (int q = 0; q < 2; ++q){
      int ch = t2 + 128 * q;
      uint4 v = s[ch];
      float* d = &xdst[ch * 8];
      d[0] = bl16(v.x); d[1] = bh16(v.x);
      d[2] = bl16(v.y); d[3] = bh16(v.y);
      d[4] = bl16(v.z); d[5] = bh16(v.z);
      d[6] = bl16(v.w); d[7] = bh16(v.w);
    }
  } else {
    const float4* s = (const float4*)((const float*)xraw + (size_t)bt * 2048);
    #pragma unroll
    for (int q = 0; q < 4; ++q){
      int ch = t2 + 128 * q;
      *(float4*)&xdst[ch * 4] = s[ch];
    }
  }
  if (tid < DD) vxs[tid] = vx[tid];
  __syncthreads();

  int m = t2 >> 3, cc = t2 & 7;
  float p = 0.f;
  #pragma unroll
  for (int j = 0; j < 16; ++j)
    p = fmaf(xs[half][m][cc * 16 + j], vxs[cc * 16 + j], p);
  part[half][t2] = p;
  __syncthreads();
  if (t2 < MM){
    float s = 0.f;
    #pragma unroll
    for (int q = 0; q < 8; ++q) s += part[half][t2 * 8 + q];
    sc[half][t2] = s;
  }
  __syncthreads();

  float mx = sc[half][0];
  #pragma unroll
  for (int m2 = 1; m2 < MM; ++m2) mx = fmaxf(mx, sc[half][m2]);
  float wgt[MM]; float den = 0.f;
  #pragma unroll
  for (int m2 = 0; m2 < MM; ++m2){ wgt[m2] = __expf(sc[half][m2] - mx); den += wgt[m2]; }
  float inv = 1.0f / den;

  float acc = 0.f;
  #pragma unroll
  for (int m2 = 0; m2 < MM; ++m2)
    acc = fmaf(wgt[m2], xs[half][m2][t2], acc);
  newx[((size_t)t * BB + b) * DD + t2] = __float2bfloat16(acc * inv);
}

// ---------------- K2: Xp[r, g*128+j] = b_g[j] + sum_d new_x[r,d] * W_g[d,j] ---------
__global__ __launch_bounds__(256) void k_xproj(const __hip_bfloat16* __restrict__ nx,
  const void* __restrict__ W0, const void* __restrict__ W1,
  const void* __restrict__ W2, const void* __restrict__ W3,
  const void* __restrict__ b0_, const void* __restrict__ b1_,
  const void* __restrict__ b2_, const void* __restrict__ b3_,
  const int* __restrict__ flag, float* __restrict__ Xp)
{
  __shared__ __hip_bfloat16 As[128][DD];  // 32 KB
  __shared__ __hip_bfloat16 Ws[DD][HH];   // 32 KB
  int mode = *flag;
  int tid = threadIdx.x;
  int r0 = blockIdx.x * 128;
  int g  = blockIdx.y;
  const void* W  = (g == 0) ? W0  : (g == 1) ? W1  : (g == 2) ? W2  : W3;
  const void* bb = (g == 0) ? b0_ : (g == 1) ? b1_ : (g == 2) ? b2_ : b3_;

  const uint4* asrc = (const uint4*)(nx + (size_t)r0 * DD);
  uint4* adst = (uint4*)&As[0][0];
  uint4* wdst = (uint4*)&Ws[0][0];
  #pragma unroll
  for (int q = 0; q < 8; ++q) adst[q * 256 + tid] = asrc[q * 256 + tid];

  if (mode){
    const uint4* wsrc = (const uint4*)W;
    #pragma unroll
    for (int q = 0; q < 8; ++q) wdst[q * 256 + tid] = wsrc[q * 256 + tid];
  } else {
    const float4* wsrc = (const float4*)W;
    #pragma unroll
    for (int q = 0; q < 8; ++q){
      int ch = q * 256 + tid;
      float4 a = wsrc[2 * ch], b = wsrc[2 * ch + 1];
      uint4 o;
      o.x = (uint)f2bu(a.x) | ((uint)f2bu(a.y) << 16);
      o.y = (uint)f2bu(a.z) | ((uint)f2bu(a.w) << 16);
      o.z = (uint)f2bu(b.x) | ((uint)f2bu(b.y) << 16);
      o.w = (uint)f2bu(b.z) | ((uint)f2bu(b.w) << 16);
      wdst[ch] = o;
    }
  }
  __syncthreads();

  int ti = tid >> 4, tj = tid & 15;
  int i0 = ti * 8, j0 = tj * 8;
  float acc[8][8] = {};

  for (int k = 0; k < DD; k += 8){
    float a[8][8];
    #pragma unroll
    for (int ii = 0; ii < 8; ++ii){
      uint4 v = *(const uint4*)&As[i0 + ii][k];
      a[ii][0] = bl16(v.x); a[ii][1] = bh16(v.x);
      a[ii][2] = bl16(v.y); a[ii][3] = bh16(v.y);
      a[ii][4] = bl16(v.z); a[ii][5] = bh16(v.z);
      a[ii][6] = bl16(v.w); a[ii][7] = bh16(v.w);
    }
    #pragma unroll
    for (int kk = 0; kk < 8; ++kk){
      uint4 v = *(const uint4*)&Ws[k + kk][j0];
      float w[8];
      w[0] = bl16(v.x); w[1] = bh16(v.x);
      w[2] = bl16(v.y); w[3] = bh16(v.y);
      w[4] = bl16(v.z); w[5] = bh16(v.z);
      w[6] = bl16(v.w); w[7] = bh16(v.w);
      #pragma unroll
      for (int ii = 0; ii < 8; ++ii)
        #pragma unroll
        for (int jj = 0; jj < 8; ++jj)
          acc[ii][jj] = fmaf(a[ii][kk], w[jj], acc[ii][jj]);
    }
  }

  float bias[8];
  if (mode){
    #pragma unroll
    for (int jj = 0; jj < 8; ++jj)
      bias[jj] = __uint_as_float(((uint)((const ushort*)bb)[j0 + jj]) << 16);
  } else {
    #pragma unroll
    for (int jj = 0; jj < 8; ++jj) bias[jj] = ((const float*)bb)[j0 + jj];
  }
  #pragma unroll
  for (int ii = 0; ii < 8; ++ii){
    size_t r = (size_t)(r0 + i0 + ii);
    float* orow = &Xp[r * 512 + g * HH + j0];
    float4 o1 = make_float4(acc[ii][0] + bias[0], acc[ii][1] + bias[1],
                            acc[ii][2] + bias[2], acc[ii][3] + bias[3]);
    float4 o2 = make_float4(acc[ii][4] + bias[4], acc[ii][5] + bias[5],
                            acc[ii][6] + bias[6], acc[ii][7] + bias[7]);
    *(float4*)orow       = o1;
    *(float4*)(orow + 4) = o2;
  }
}

// ---------------- K3: recurrence on the MATRIX pipe ---------------------------------
// R13: R11/R12 established the dot2 formulation is saturated (~500+ issue-cyc/SIMD/
// step; removing work = null, adding work = proportional). Move h@U to MFMA:
//  - wave w owns output cols w*16..w*16+15 for ALL 4 gates (N-tiles g=0..3).
//  - A-frag = h broadcast to all 16 rows (lane's 8 f16 = h[kc*32+(l>>4)*8+e]) ->
//    every C row identical -> only the (verified) col=lane&15 C mapping matters,
//    and common k-permutations between A-fill and B-pack cancel.
//  - C initialized with Xp (bias folded) -> after 16 MFMAs lane holds p_i,p_f,p_c,p_o
//    for col lane&15. No qsum, no cross-lane reduce; gates are short per-lane VALU.
//  - Xp prefetch distance 2 via 2x-unrolled register sets; non-draining barrier
//    (lgkmcnt only) keeps the global loads in flight across steps.
__global__ __attribute__((amdgpu_waves_per_eu(2, 2))) __launch_bounds__(512)
void k_rec(const float* __restrict__ Xp, const uint4* __restrict__ Uw,
           float* __restrict__ out)
{
  __shared__ __align__(16) __half hlds[2][HH];   // 512 B double-buffered h
  int tid  = threadIdx.x;
  int b    = blockIdx.x;
  int w    = tid >> 6;          // wave id: col block w*16..w*16+15
  int lane = tid & 63;
  int l16  = lane & 15;

  // ---- B-frags: Ub[g*4+kc], 16 coalesced dwordx4 loads ----
  f16x8 Ub[16];
  #pragma unroll
  for (int g = 0; g < 4; ++g)
    #pragma unroll
    for (int kc = 0; kc < 4; ++kc){
      uint4 v = Uw[((g * 4 + kc) * 8 + w) * 64 + lane];
      union{uint4 u; f16x8 h;} cv; cv.u = v;
      Ub[g * 4 + kc] = cv.h;
    }

  // ---- per-thread Xp column pointer; prime t=0,1 ----
  const float* xcol = Xp + (size_t)b * 512 + w * 16 + l16;
  float xpA[4], xpB[4];
  #pragma unroll
  for (int g = 0; g < 4; ++g) xpA[g] = xcol[g * 128];
  #pragma unroll
  for (int g = 0; g < 4; ++g) xpB[g] = xcol[(size_t)(BB * 512) + g * 128];

  if (tid < 64) ((uint*)&hlds[0][0])[tid] = 0;   // h(0) = 0 (128 f16)
  float cst = 0.f, vh = 0.f;
  const int lo = (lane >> 4) * 16;               // byte offset of lane's k-slice
  __syncthreads();

#define STEP(T, XP) do{                                                        \
    const char* hb = (const char*)&hlds[(T) & 1][0];                           \
    f16x8 a0 = *(const f16x8*)(hb +   0 + lo);                                 \
    f16x8 a1 = *(const f16x8*)(hb +  64 + lo);                                 \
    f16x8 a2 = *(const f16x8*)(hb + 128 + lo);                                 \
    f16x8 a3 = *(const f16x8*)(hb + 192 + lo);                                 \
    f32x4 c0 = {XP[0], XP[0], XP[0], XP[0]};                                   \
    f32x4 c1 = {XP[1], XP[1], XP[1], XP[1]};                                   \
    f32x4 c2 = {XP[2], XP[2], XP[2], XP[2]};                                   \
    f32x4 c3 = {XP[3], XP[3], XP[3], XP[3]};                                   \
    c0 = __builtin_amdgcn_mfma_f32_16x16x32_f16(a0, Ub[ 0], c0, 0, 0, 0);      \
    c1 = __builtin_amdgcn_mfma_f32_16x16x32_f16(a0, Ub[ 4], c1, 0, 0, 0);      \
    c2 = __builtin_amdgcn_mfma_f32_16x16x32_f16(a0, Ub[ 8], c2, 0, 0, 0);      \
    c3 = __builtin_amdgcn_mfma_f32_16x16x32_f16(a0, Ub[12], c3, 0, 0, 0);      \
    c0 = __builtin_amdgcn_mfma_f32_16x16x32_f16(a1, Ub[ 1], c0, 0, 0, 0);      \
    c1 = __builtin_amdgcn_mfma_f32_16x16x32_f16(a1, Ub[ 5], c1, 0, 0, 0);      \
    c2 = __builtin_amdgcn_mfma_f32_16x16x32_f16(a1, Ub[ 9], c2, 0, 0, 0);      \
    c3 = __builtin_amdgcn_mfma_f32_16x16x32_f16(a1, Ub[13], c3, 0, 0, 0);      \
    c0 = __builtin_amdgcn_mfma_f32_16x16x32_f16(a2, Ub[ 2], c0, 0, 0, 0);      \
    c1 = __builtin_amdgcn_mfma_f32_16x16x32_f16(a2, Ub[ 6], c1, 0, 0, 0);      \
    c2 = __builtin_amdgcn_mfma_f32_16x16x32_f16(a2, Ub[10], c2, 0, 0, 0);      \
    c3 = __builtin_amdgcn_mfma_f32_16x16x32_f16(a2, Ub[14], c3, 0, 0, 0);      \
    c0 = __builtin_amdgcn_mfma_f32_16x16x32_f16(a3, Ub[ 3], c0, 0, 0, 0);      \
    c1 = __builtin_amdgcn_mfma_f32_16x16x32_f16(a3, Ub[ 7], c1, 0, 0, 0);      \
    c2 = __builtin_amdgcn_mfma_f32_16x16x32_f16(a3, Ub[11], c2, 0, 0, 0);      \
    c3 = __builtin_amdgcn_mfma_f32_16x16x32_f16(a3, Ub[15], c3, 0, 0, 0);      \
    float ig = hsig(c0[0]), fg = hsig(c1[0]), og = hsig(c3[0]);                \
    float gg = tanh_f(c2[0]);                                                  \
    cst = fmaf(fg, cst, ig * gg);                                              \
    vh  = og * tanh_f(cst);                                                    \
    if (lane < 16) hlds[((T) + 1) & 1][w * 16 + lane] = __float2half(vh);      \
    {                                                                          \
      int tp = (T) + 2; if (tp > TT - 1) tp = TT - 1;                          \
      const float* xs = xcol + ((size_t)tp << 14);                             \
      _Pragma("unroll")                                                        \
      for (int g = 0; g < 4; ++g) XP[g] = xs[g * 128];                         \
    }                                                                          \
    asm volatile("s_waitcnt lgkmcnt(0)" ::: "memory");                         \
    __builtin_amdgcn_s_barrier();                                              \
    asm volatile("" ::: "memory");                                             \
  }while(0)

  for (int t = 0; t < TT; t += 2){
    STEP(t,     xpA);
    STEP(t + 1, xpB);
  }
#undef STEP

  if (lane < 16) out[b * HH + w * 16 + lane] = vh;
}

extern "C" void kernel_launch(void* const* d_in, const int* in_sizes, int n_in,
                              void* d_out, int out_size, void* d_ws, size_t ws_size,
                              hipStream_t stream) {
  (void)in_sizes; (void)n_in; (void)out_size; (void)ws_size;

  // ---- workspace layout (~18.2 MB) ----
  // [0,16)            flag
  // [16,528)          vx fp32[128]
  // [1024, +128KB)    Uw uint4[8192]  (MFMA B-fragments, f16)
  // [+, +2MB)         newx bf16[8192*128]
  // [+, +16MB)        Xp fp32[8192*512]
  char* ws = (char*)d_ws;
  int* flag = (int*)ws;
  float* vx = (float*)(ws + 16);
  uint4* Uw = (uint4*)(ws + 1024);
  __hip_bfloat16* newx = (__hip_bfloat16*)(ws + 1024 + 131072);
  float* Xp = (float*)(ws + 1024 + 131072 + (size_t)2 * 1024 * 1024);

  k_init<<<1, 128, 0, stream>>>(d_in[0], d_in[1], flag, vx);
  k_uprep2<<<32, 256, 0, stream>>>(d_in[4], d_in[7], d_in[10], d_in[13], flag, Uw);  // U_i,U_f,U_c,U_o
  k_pool<<<BB * TT / 2, 256, 0, stream>>>(d_in[0], flag, vx, newx);
  dim3 g2(64, 4);
  k_xproj<<<g2, 256, 0, stream>>>(newx,
      d_in[3], d_in[6], d_in[9], d_in[12],     // W_i, W_f, W_c, W_o
      d_in[5], d_in[8], d_in[11], d_in[14],    // b_i, b_f, b_c, b_o
      flag, Xp);
  k_rec<<<BB, 512, 0, stream>>>(Xp, Uw, (float*)d_out);
}

// Round 4
// 251.885 us; speedup vs baseline: 1.3412x; 1.0702x over previous
//
#include <hip/hip_runtime.h>
#include <hip/hip_bf16.h>
#include <hip/hip_fp16.h>

#define BB 32
#define TT 256
#define MM 16
#define DD 128
#define HH 128

typedef unsigned int uint;
typedef unsigned short ushort;

typedef _Float16 f16;
typedef _Float16 f16x8 __attribute__((ext_vector_type(8)));
typedef float f32x4 __attribute__((ext_vector_type(4)));

__device__ __forceinline__ float bl16(uint u){ return __uint_as_float(u << 16); }
__device__ __forceinline__ float bh16(uint u){ return __uint_as_float(u & 0xffff0000u); }

__device__ __forceinline__ float hsig(float x){
  // clamp(0.2x+0.5, 0, 1) via v_med3_f32
  return __builtin_amdgcn_fmed3f(fmaf(x, 0.2f, 0.5f), 0.0f, 1.0f);
}
__device__ __forceinline__ float tanh_f(float x){
  return 1.0f - 2.0f / (__expf(2.0f * x) + 1.0f);   // saturates correctly
}

__device__ __forceinline__ uint packh2(float a, float b){
  __half2 hv = __floats2half2_rn(a, b);
  union{__half2 h; uint x;} cv; cv.h = hv; return cv.x;
}

// ---------------- K_prep: fused {dtype probe + U-pack + W-pack + vx/flag} -----------
// 65 blocks x 256: blocks 0-31 pack {U_i,U_f,U_c,U_o} -> Uw (MFMA B-frags, f16);
// blocks 32-63 pack {W_i,W_f,W_c,W_o} -> Ww (same layout); block 64 computes
// vx[d] = sum_h W_a[d,h] and writes *flag. Every block self-probes the dtype (4KB,
// L2-hot) so there is no cross-block dependency and no solo-block serial phase
// (old k_init ran 1 block alone on the whole GPU).
// Frag layout (R3-verified): frag f = (g*4+kc)*8 + cb; lane l, elem e: M[k][c] with
// k = kc*32 + (l>>4)*8 + e, c = cb*16 + (l&15). dst[f*64+l] = 8 f16, pair low-first.
__global__ __launch_bounds__(256) void k_prep(
  const void* __restrict__ xraw, const void* __restrict__ Wa,
  const void* __restrict__ U0, const void* __restrict__ U1,
  const void* __restrict__ U2, const void* __restrict__ U3,
  const void* __restrict__ W0, const void* __restrict__ W1,
  const void* __restrict__ W2, const void* __restrict__ W3,
  int* __restrict__ flag, float* __restrict__ vx,
  uint4* __restrict__ Uw, uint4* __restrict__ Ww)
{
  __shared__ int cnt[256];
  __shared__ int smode;
  int tid = threadIdx.x;
  int bid = blockIdx.x;

  // self-probe: same 2048 samples as the old k_init
  {
    const ushort* u = (const ushort*)xraw;
    int c = 0;
    #pragma unroll
    for (int j = 0; j < 8; ++j){
      ushort v = u[2 * (tid * 8 + j)];
      float f = __uint_as_float(((uint)v) << 16);
      if (f == f && fabsf(f) < 64.f && fabsf(f) > 1e-12f) ++c;
    }
    cnt[tid] = c;
    __syncthreads();
    if (tid == 0){
      int s = 0;
      for (int i = 0; i < 256; ++i) s += cnt[i];
      smode = (s > 1024) ? 1 : 0;
    }
    __syncthreads();
  }
  int mode = smode;

  if (bid < 64){
    // ---- pack one quartet element ----
    int idx = (bid & 31) * 256 + tid;      // 0..8191
    int f = idx >> 6, lane = idx & 63;
    int g = f >> 5, kc = (f >> 3) & 3, cb = f & 7;
    int k0 = kc * 32 + (lane >> 4) * 8;
    int c  = cb * 16 + (lane & 15);
    const void* Ms[4];
    if (bid < 32){ Ms[0] = U0; Ms[1] = U1; Ms[2] = U2; Ms[3] = U3; }
    else         { Ms[0] = W0; Ms[1] = W1; Ms[2] = W2; Ms[3] = W3; }
    float v[8];
    if (mode){
      const ushort* U = (const ushort*)Ms[g];
      #pragma unroll
      for (int e = 0; e < 8; ++e)
        v[e] = __uint_as_float(((uint)U[(size_t)(k0 + e) * HH + c]) << 16);
    } else {
      const float* U = (const float*)Ms[g];
      #pragma unroll
      for (int e = 0; e < 8; ++e)
        v[e] = U[(size_t)(k0 + e) * HH + c];
    }
    uint4 o;
    o.x = packh2(v[0], v[1]); o.y = packh2(v[2], v[3]);
    o.z = packh2(v[4], v[5]); o.w = packh2(v[6], v[7]);
    ((bid < 32) ? Uw : Ww)[idx] = o;
  } else {
    // ---- vx + flag ----
    if (tid == 0) *flag = mode;
    if (tid < 128){
      int d = tid;
      float s = 0.f;
      if (mode){
        const uint4* row = (const uint4*)((const ushort*)Wa + d * HH);
        #pragma unroll
        for (int q = 0; q < 16; ++q){
          uint4 v = row[q];
          s += bl16(v.x) + bh16(v.x) + bl16(v.y) + bh16(v.y)
             + bl16(v.z) + bh16(v.z) + bl16(v.w) + bh16(v.w);
        }
      } else {
        const float4* row = (const float4*)((const float*)Wa + d * HH);
        #pragma unroll
        for (int q = 0; q < 32; ++q){
          float4 v = row[q];
          s += v.x + v.y + v.z + v.w;
        }
      }
      vx[d] = s;
    }
  }
}

// ---------------- K1: softmax-pool, 2 (b,t)-tiles per block (f16 out) ---------------
__global__ __launch_bounds__(256) void k_pool(const void* __restrict__ xraw,
                                              const int* __restrict__ flag,
                                              const float* __restrict__ vx,
                                              __half* __restrict__ newx){
  __shared__ float xs[2][MM][DD];   // 16 KB
  __shared__ float vxs[DD];
  __shared__ float part[2][128];
  __shared__ float sc[2][MM];
  int mode = *flag;
  int tid = threadIdx.x;
  int half = tid >> 7, t2 = tid & 127;
  int bt = blockIdx.x * 2 + half;       // tile 0..8191
  int b = bt >> 8, t = bt & 255;

  float* xdst = &xs[half][0][0];        // 2048 floats per tile
  if (mode){
    const uint4* s = (const uint4*)((const ushort*)xraw + (size_t)bt * 2048);
    #pragma unroll
    for (int q = 0; q < 2; ++q){
      int ch = t2 + 128 * q;
      uint4 v = s[ch];
      float* d = &xdst[ch * 8];
      d[0] = bl16(v.x); d[1] = bh16(v.x);
      d[2] = bl16(v.y); d[3] = bh16(v.y);
      d[4] = bl16(v.z); d[5] = bh16(v.z);
      d[6] = bl16(v.w); d[7] = bh16(v.w);
    }
  } else {
    const float4* s = (const float4*)((const float*)xraw + (size_t)bt * 2048);
    #pragma unroll
    for (int q = 0; q < 4; ++q){
      int ch = t2 + 128 * q;
      *(float4*)&xdst[ch * 4] = s[ch];
    }
  }
  if (tid < DD) vxs[tid] = vx[tid];
  __syncthreads();

  int m = t2 >> 3, cc = t2 & 7;
  float p = 0.f;
  #pragma unroll
  for (int j = 0; j < 16; ++j)
    p = fmaf(xs[half][m][cc * 16 + j], vxs[cc * 16 + j], p);
  part[half][t2] = p;
  __syncthreads();
  if (t2 < MM){
    float s = 0.f;
    #pragma unroll
    for (int q = 0; q < 8; ++q) s += part[half][t2 * 8 + q];
    sc[half][t2] = s;
  }
  __syncthreads();

  float mx = sc[half][0];
  #pragma unroll
  for (int m2 = 1; m2 < MM; ++m2) mx = fmaxf(mx, sc[half][m2]);
  float wgt[MM]; float den = 0.f;
  #pragma unroll
  for (int m2 = 0; m2 < MM; ++m2){ wgt[m2] = __expf(sc[half][m2] - mx); den += wgt[m2]; }
  float inv = 1.0f / den;

  float acc = 0.f;
  #pragma unroll
  for (int m2 = 0; m2 < MM; ++m2)
    acc = fmaf(wgt[m2], xs[half][m2][t2], acc);
  newx[((size_t)t * BB + b) * DD + t2] = __float2half(acc * inv);
}

// ---------------- K2: MFMA x-projection -------------------------------------------
// Xp[r, G*128+j] = b_G[j] + sum_d newx[r,d] * W_G[d,j], as f16 MFMA GEMM.
// R4: replaces the fp32-VALU tile GEMM (est 15-25us) with 16x16x32 f16 MFMA (~3-5us).
// Per block: 128 rows x 128 cols, K=128. 4 waves, wave w owns rows w*32..w*32+32.
// A staged in LDS with 16B-granule XOR swizzle (granule ^= row&15) -> A-frag
// ds_read_b128 lands 2-way bank aliased (free, m136). B-frags come pre-packed from
// Ww (k_prep), coalesced dwordx4, L2-resident. C mapping col=lane&15,
// row=(lane>>4)*4+reg (m89-verified); A row map m=lane&15 is the one new assumption.
__global__ __launch_bounds__(256) void k_xproj(const __half* __restrict__ nx,
  const uint4* __restrict__ Ww,
  const void* __restrict__ b0_, const void* __restrict__ b1_,
  const void* __restrict__ b2_, const void* __restrict__ b3_,
  const int* __restrict__ flag, float* __restrict__ Xp)
{
  __shared__ __align__(16) char As[32768];   // [128 rows][16 granules x 16B], swizzled
  int tid = threadIdx.x;
  int r0 = blockIdx.x * 128;
  int G  = blockIdx.y;
  int lane = tid & 63, w = tid >> 6;
  int l16 = lane & 15, lq = lane >> 4;

  // stage newx rows r0..r0+127 (256B rows), swizzled: granule c16 -> c16 ^ (r&15)
  {
    const uint4* src = (const uint4*)(nx + (size_t)r0 * DD);
    uint4* dst = (uint4*)As;
    #pragma unroll
    for (int i = 0; i < 8; ++i){
      int gid = i * 256 + tid;           // 0..2047
      int r = gid >> 4, c16 = gid & 15;
      dst[r * 16 + (c16 ^ (r & 15))] = src[gid];
    }
  }

  int mode = *flag;
  const void* bb = (G == 0) ? b0_ : (G == 1) ? b1_ : (G == 2) ? b2_ : b3_;
  float bias[8];
  #pragma unroll
  for (int cb = 0; cb < 8; ++cb){
    int col = cb * 16 + l16;
    bias[cb] = mode ? __uint_as_float(((uint)((const ushort*)bb)[col]) << 16)
                    : ((const float*)bb)[col];
  }
  __syncthreads();

  int rb = w * 32;                       // wave's row block
  f32x4 acc[2][8];
  #pragma unroll
  for (int mt = 0; mt < 2; ++mt)
    #pragma unroll
    for (int cb = 0; cb < 8; ++cb)
      acc[mt][cb] = (f32x4){bias[cb], bias[cb], bias[cb], bias[cb]};

  #pragma unroll
  for (int kc = 0; kc < 4; ++kc){
    f16x8 a[2];
    #pragma unroll
    for (int mt = 0; mt < 2; ++mt){
      int r = rb + mt * 16 + l16;
      int g16 = (kc * 4 + lq) ^ (r & 15);
      a[mt] = *(const f16x8*)(As + r * 256 + g16 * 16);
    }
    #pragma unroll
    for (int cb = 0; cb < 8; ++cb){
      union{uint4 u; f16x8 h;} bv;
      bv.u = Ww[((size_t)((G * 4 + kc) * 8 + cb)) * 64 + lane];
      acc[0][cb] = __builtin_amdgcn_mfma_f32_16x16x32_f16(a[0], bv.h, acc[0][cb], 0, 0, 0);
      acc[1][cb] = __builtin_amdgcn_mfma_f32_16x16x32_f16(a[1], bv.h, acc[1][cb], 0, 0, 0);
    }
  }

  #pragma unroll
  for (int mt = 0; mt < 2; ++mt)
    #pragma unroll
    for (int cb = 0; cb < 8; ++cb)
      #pragma unroll
      for (int reg = 0; reg < 4; ++reg){
        size_t r = (size_t)(r0 + rb + mt * 16 + lq * 4 + reg);
        Xp[r * 512 + G * HH + cb * 16 + l16] = acc[mt][cb][reg];
      }
}

// ---------------- K3: recurrence on the MATRIX pipe ---------------------------------
// R4 vs R3 (124.6us): 8 independent depth-2 MFMA chains (was 4 chains of depth 4)
// -> dependent-MFMA tail is 2 latencies, not 4; costs 4 scalar adds (only elem [0]
// of each accumulator is ever read, since A is h broadcast to all 16 rows).
// Everything else unchanged: non-draining barrier (lgkmcnt only), distance-2 Xp
// prefetch through 2x-unrolled register sets.
__global__ __attribute__((amdgpu_waves_per_eu(2, 2))) __launch_bounds__(512)
void k_rec(const float* __restrict__ Xp, const uint4* __restrict__ Uw,
           float* __restrict__ out)
{
  __shared__ __align__(16) __half hlds[2][HH];   // 512 B double-buffered h
  int tid  = threadIdx.x;
  int b    = blockIdx.x;
  int w    = tid >> 6;          // wave id: col block w*16..w*16+15
  int lane = tid & 63;
  int l16  = lane & 15;

  // ---- B-frags: Ub[g*4+kc], 16 coalesced dwordx4 loads ----
  f16x8 Ub[16];
  #pragma unroll
  for (int g = 0; g < 4; ++g)
    #pragma unroll
    for (int kc = 0; kc < 4; ++kc){
      uint4 v = Uw[((g * 4 + kc) * 8 + w) * 64 + lane];
      union{uint4 u; f16x8 h;} cv; cv.u = v;
      Ub[g * 4 + kc] = cv.h;
    }

  // ---- per-thread Xp column pointer; prime t=0,1 ----
  const float* xcol = Xp + (size_t)b * 512 + w * 16 + l16;
  float xpA[4], xpB[4];
  #pragma unroll
  for (int g = 0; g < 4; ++g) xpA[g] = xcol[g * 128];
  #pragma unroll
  for (int g = 0; g < 4; ++g) xpB[g] = xcol[(size_t)(BB * 512) + g * 128];

  if (tid < 64) ((uint*)&hlds[0][0])[tid] = 0;   // h(0) = 0 (128 f16)
  float cst = 0.f, vh = 0.f;
  const int lo = (lane >> 4) * 16;               // byte offset of lane's k-slice
  __syncthreads();

#define STEP(T, XP) do{                                                        \
    const char* hb = (const char*)&hlds[(T) & 1][0];                           \
    f16x8 a0 = *(const f16x8*)(hb +   0 + lo);                                 \
    f16x8 a1 = *(const f16x8*)(hb +  64 + lo);                                 \
    f16x8 a2 = *(const f16x8*)(hb + 128 + lo);                                 \
    f16x8 a3 = *(const f16x8*)(hb + 192 + lo);                                 \
    f32x4 c0 = {XP[0], XP[0], XP[0], XP[0]};                                   \
    f32x4 c1 = {XP[1], XP[1], XP[1], XP[1]};                                   \
    f32x4 c2 = {XP[2], XP[2], XP[2], XP[2]};                                   \
    f32x4 c3 = {XP[3], XP[3], XP[3], XP[3]};                                   \
    f32x4 d0 = {0.f, 0.f, 0.f, 0.f};                                           \
    f32x4 d1 = {0.f, 0.f, 0.f, 0.f};                                           \
    f32x4 d2 = {0.f, 0.f, 0.f, 0.f};                                           \
    f32x4 d3 = {0.f, 0.f, 0.f, 0.f};                                           \
    c0 = __builtin_amdgcn_mfma_f32_16x16x32_f16(a0, Ub[ 0], c0, 0, 0, 0);      \
    c1 = __builtin_amdgcn_mfma_f32_16x16x32_f16(a0, Ub[ 4], c1, 0, 0, 0);      \
    c2 = __builtin_amdgcn_mfma_f32_16x16x32_f16(a0, Ub[ 8], c2, 0, 0, 0);      \
    c3 = __builtin_amdgcn_mfma_f32_16x16x32_f16(a0, Ub[12], c3, 0, 0, 0);      \
    d0 = __builtin_amdgcn_mfma_f32_16x16x32_f16(a2, Ub[ 2], d0, 0, 0, 0);      \
    d1 = __builtin_amdgcn_mfma_f32_16x16x32_f16(a2, Ub[ 6], d1, 0, 0, 0);      \
    d2 = __builtin_amdgcn_mfma_f32_16x16x32_f16(a2, Ub[10], d2, 0, 0, 0);      \
    d3 = __builtin_amdgcn_mfma_f32_16x16x32_f16(a2, Ub[14], d3, 0, 0, 0);      \
    c0 = __builtin_amdgcn_mfma_f32_16x16x32_f16(a1, Ub[ 1], c0, 0, 0, 0);      \
    c1 = __builtin_amdgcn_mfma_f32_16x16x32_f16(a1, Ub[ 5], c1, 0, 0, 0);      \
    c2 = __builtin_amdgcn_mfma_f32_16x16x32_f16(a1, Ub[ 9], c2, 0, 0, 0);      \
    c3 = __builtin_amdgcn_mfma_f32_16x16x32_f16(a1, Ub[13], c3, 0, 0, 0);      \
    d0 = __builtin_amdgcn_mfma_f32_16x16x32_f16(a3, Ub[ 3], d0, 0, 0, 0);      \
    d1 = __builtin_amdgcn_mfma_f32_16x16x32_f16(a3, Ub[ 7], d1, 0, 0, 0);      \
    d2 = __builtin_amdgcn_mfma_f32_16x16x32_f16(a3, Ub[11], d2, 0, 0, 0);      \
    d3 = __builtin_amdgcn_mfma_f32_16x16x32_f16(a3, Ub[15], d3, 0, 0, 0);      \
    float p0 = c0[0] + d0[0];                                                  \
    float p1 = c1[0] + d1[0];                                                  \
    float p2 = c2[0] + d2[0];                                                  \
    float p3 = c3[0] + d3[0];                                                  \
    float ig = hsig(p0), fg = hsig(p1), og = hsig(p3);                         \
    float gg = tanh_f(p2);                                                     \
    cst = fmaf(fg, cst, ig * gg);                                              \
    vh  = og * tanh_f(cst);                                                    \
    if (lane < 16) hlds[((T) + 1) & 1][w * 16 + lane] = __float2half(vh);      \
    {                                                                          \
      int tp = (T) + 2; if (tp > TT - 1) tp = TT - 1;                          \
      const float* xs = xcol + ((size_t)tp << 14);                             \
      _Pragma("unroll")                                                        \
      for (int g = 0; g < 4; ++g) XP[g] = xs[g * 128];                         \
    }                                                                          \
    asm volatile("s_waitcnt lgkmcnt(0)" ::: "memory");                         \
    __builtin_amdgcn_s_barrier();                                              \
    asm volatile("" ::: "memory");                                             \
  }while(0)

  for (int t = 0; t < TT; t += 2){
    STEP(t,     xpA);
    STEP(t + 1, xpB);
  }
#undef STEP

  if (lane < 16) out[b * HH + w * 16 + lane] = vh;
}

extern "C" void kernel_launch(void* const* d_in, const int* in_sizes, int n_in,
                              void* d_out, int out_size, void* d_ws, size_t ws_size,
                              hipStream_t stream) {
  (void)in_sizes; (void)n_in; (void)out_size; (void)ws_size;

  // ---- workspace layout (~18.4 MB) ----
  // [0,16)            flag
  // [16,528)          vx fp32[128]
  // [1024, +128KB)    Uw uint4[8192]  (MFMA B-fragments of U, f16)
  // [+, +128KB)       Ww uint4[8192]  (MFMA B-fragments of W, f16)
  // [+, +2MB)         newx f16[8192*128]
  // [+, +16MB)        Xp fp32[8192*512]
  char* ws = (char*)d_ws;
  int* flag = (int*)ws;
  float* vx = (float*)(ws + 16);
  uint4* Uw = (uint4*)(ws + 1024);
  uint4* Ww = (uint4*)(ws + 1024 + 131072);
  __half* newx = (__half*)(ws + 1024 + 2 * 131072);
  float* Xp = (float*)(ws + 1024 + 2 * 131072 + (size_t)2 * 1024 * 1024);

  k_prep<<<65, 256, 0, stream>>>(d_in[0], d_in[1],
      d_in[4], d_in[7], d_in[10], d_in[13],    // U_i, U_f, U_c, U_o
      d_in[3], d_in[6], d_in[9],  d_in[12],    // W_i, W_f, W_c, W_o
      flag, vx, Uw, Ww);
  k_pool<<<BB * TT / 2, 256, 0, stream>>>(d_in[0], flag, vx, newx);
  dim3 g2(64, 4);
  k_xproj<<<g2, 256, 0, stream>>>(newx, Ww,
      d_in[5], d_in[8], d_in[11], d_in[14],    // b_i, b_f, b_c, b_o
      flag, Xp);
  k_rec<<<BB, 512, 0, stream>>>(Xp, Uw, (float*)d_out);
}

// Round 5
// 251.728 us; speedup vs baseline: 1.3421x; 1.0006x over previous
//
#include <hip/hip_runtime.h>
#include <hip/hip_bf16.h>
#include <hip/hip_fp16.h>

#define BB 32
#define TT 256
#define MM 16
#define DD 128
#define HH 128

typedef unsigned int uint;
typedef unsigned short ushort;

typedef _Float16 f16;
typedef _Float16 f16x8 __attribute__((ext_vector_type(8)));
typedef float f32x4 __attribute__((ext_vector_type(4)));

__device__ __forceinline__ float bl16(uint u){ return __uint_as_float(u << 16); }
__device__ __forceinline__ float bh16(uint u){ return __uint_as_float(u & 0xffff0000u); }

__device__ __forceinline__ float hsig(float x){
  // clamp(0.2x+0.5, 0, 1) via v_med3_f32
  return __builtin_amdgcn_fmed3f(fmaf(x, 0.2f, 0.5f), 0.0f, 1.0f);
}
__device__ __forceinline__ float tanh_f(float x){
  return 1.0f - 2.0f / (__expf(2.0f * x) + 1.0f);   // saturates correctly
}

__device__ __forceinline__ uint packh2(float a, float b){
  __half2 hv = __floats2half2_rn(a, b);
  union{__half2 h; uint x;} cv; cv.h = hv; return cv.x;
}

// quad_perm butterfly: all 4 quad lanes end with the quad sum
__device__ __forceinline__ float qsum4(float v){
  float t1 = __int_as_float(__builtin_amdgcn_mov_dpp(__float_as_int(v), 0xB1, 0xf, 0xf, true)); // [1,0,3,2]
  v += t1;
  float t2 = __int_as_float(__builtin_amdgcn_mov_dpp(__float_as_int(v), 0x4E, 0xf, 0xf, true)); // [2,3,0,1]
  return v + t2;
}

// ---------------- K_prep: fused {dtype probe + U-pack + W-pack + vx/flag} -----------
// 65 blocks x 256: blocks 0-31 pack {U_i,U_f,U_c,U_o} -> Uw (MFMA B-frags, f16);
// blocks 32-63 pack {W_i,W_f,W_c,W_o} -> Ww (same layout); block 64 computes
// vx[d] = sum_h W_a[d,h] and writes *flag. Every block self-probes the dtype (4KB,
// L2-hot) so there is no cross-block dependency and no solo-block serial phase.
// Frag layout (R3-verified): frag f = (g*4+kc)*8 + cb; lane l, elem e: M[k][c] with
// k = kc*32 + (l>>4)*8 + e, c = cb*16 + (l&15). dst[f*64+l] = 8 f16, pair low-first.
__global__ __launch_bounds__(256) void k_prep(
  const void* __restrict__ xraw, const void* __restrict__ Wa,
  const void* __restrict__ U0, const void* __restrict__ U1,
  const void* __restrict__ U2, const void* __restrict__ U3,
  const void* __restrict__ W0, const void* __restrict__ W1,
  const void* __restrict__ W2, const void* __restrict__ W3,
  int* __restrict__ flag, float* __restrict__ vx,
  uint4* __restrict__ Uw, uint4* __restrict__ Ww)
{
  __shared__ int cnt[256];
  __shared__ int smode;
  int tid = threadIdx.x;
  int bid = blockIdx.x;

  // self-probe: same 2048 samples as the old k_init
  {
    const ushort* u = (const ushort*)xraw;
    int c = 0;
    #pragma unroll
    for (int j = 0; j < 8; ++j){
      ushort v = u[2 * (tid * 8 + j)];
      float f = __uint_as_float(((uint)v) << 16);
      if (f == f && fabsf(f) < 64.f && fabsf(f) > 1e-12f) ++c;
    }
    cnt[tid] = c;
    __syncthreads();
    if (tid == 0){
      int s = 0;
      for (int i = 0; i < 256; ++i) s += cnt[i];
      smode = (s > 1024) ? 1 : 0;
    }
    __syncthreads();
  }
  int mode = smode;

  if (bid < 64){
    // ---- pack one quartet element ----
    int idx = (bid & 31) * 256 + tid;      // 0..8191
    int f = idx >> 6, lane = idx & 63;
    int g = f >> 5, kc = (f >> 3) & 3, cb = f & 7;
    int k0 = kc * 32 + (lane >> 4) * 8;
    int c  = cb * 16 + (lane & 15);
    const void* Ms[4];
    if (bid < 32){ Ms[0] = U0; Ms[1] = U1; Ms[2] = U2; Ms[3] = U3; }
    else         { Ms[0] = W0; Ms[1] = W1; Ms[2] = W2; Ms[3] = W3; }
    float v[8];
    if (mode){
      const ushort* U = (const ushort*)Ms[g];
      #pragma unroll
      for (int e = 0; e < 8; ++e)
        v[e] = __uint_as_float(((uint)U[(size_t)(k0 + e) * HH + c]) << 16);
    } else {
      const float* U = (const float*)Ms[g];
      #pragma unroll
      for (int e = 0; e < 8; ++e)
        v[e] = U[(size_t)(k0 + e) * HH + c];
    }
    uint4 o;
    o.x = packh2(v[0], v[1]); o.y = packh2(v[2], v[3]);
    o.z = packh2(v[4], v[5]); o.w = packh2(v[6], v[7]);
    ((bid < 32) ? Uw : Ww)[idx] = o;
  } else {
    // ---- vx + flag ----
    if (tid == 0) *flag = mode;
    if (tid < 128){
      int d = tid;
      float s = 0.f;
      if (mode){
        const uint4* row = (const uint4*)((const ushort*)Wa + d * HH);
        #pragma unroll
        for (int q = 0; q < 16; ++q){
          uint4 v = row[q];
          s += bl16(v.x) + bh16(v.x) + bl16(v.y) + bh16(v.y)
             + bl16(v.z) + bh16(v.z) + bl16(v.w) + bh16(v.w);
        }
      } else {
        const float4* row = (const float4*)((const float*)Wa + d * HH);
        #pragma unroll
        for (int q = 0; q < 32; ++q){
          float4 v = row[q];
          s += v.x + v.y + v.z + v.w;
        }
      }
      vx[d] = s;
    }
  }
}

// ---------------- K1: softmax-pool, 2 (b,t)-tiles per block (f16 out) ---------------
// R5: score matvec fused into the STAGING loop. The old post-stage loop read
// xs[m][cc*16+j] -> addr%32 = 16(cc&1)+j: 64 lanes on 2 banks, 32 distinct addrs
// = ~32-way LDS conflict x16 iters, at 32 resident waves/CU (the suspected hidden
// ~tens-of-us). Now each thread dots its staged register values against vx (512B,
// L2-hot) and the per-row sums come from a DPP+shfl_xor lane-group reduction.
// part[]/vxs[] buffers and one __syncthreads are gone; score LDS traffic is zero.
__global__ __launch_bounds__(256) void k_pool(const void* __restrict__ xraw,
                                              const int* __restrict__ flag,
                                              const float* __restrict__ vx,
                                              __half* __restrict__ newx){
  __shared__ float xs[2][MM][DD];   // 16 KB
  __shared__ float sc[2][MM];
  int mode = *flag;
  int tid = threadIdx.x;
  int half = tid >> 7, t2 = tid & 127;
  int bt = blockIdx.x * 2 + half;       // tile 0..8191
  int b = bt >> 8, t = bt & 255;

  float* xdst = &xs[half][0][0];        // 2048 floats per tile
  if (mode){
    // staged chunk ch covers m = ch>>4, d = (ch&15)*8 .. +8; thread's 2 chunks
    // (q=0,1) share d-range (t2&15)*8 and hit m = t2>>4 and t2>>4 + 8.
    const float* vxp = vx + (t2 & 15) * 8;
    float4 vra = *(const float4*)vxp;
    float4 vrb = *(const float4*)(vxp + 4);
    const uint4* s = (const uint4*)((const ushort*)xraw + (size_t)bt * 2048);
    float sq[2];
    #pragma unroll
    for (int q = 0; q < 2; ++q){
      int ch = t2 + 128 * q;
      uint4 v = s[ch];
      float* d = &xdst[ch * 8];
      float e0 = bl16(v.x), e1 = bh16(v.x), e2 = bl16(v.y), e3 = bh16(v.y);
      float e4 = bl16(v.z), e5 = bh16(v.z), e6 = bl16(v.w), e7 = bh16(v.w);
      d[0] = e0; d[1] = e1; d[2] = e2; d[3] = e3;
      d[4] = e4; d[5] = e5; d[6] = e6; d[7] = e7;
      float p = e0 * vra.x;
      p = fmaf(e1, vra.y, p); p = fmaf(e2, vra.z, p); p = fmaf(e3, vra.w, p);
      p = fmaf(e4, vrb.x, p); p = fmaf(e5, vrb.y, p); p = fmaf(e6, vrb.z, p);
      p = fmaf(e7, vrb.w, p);
      sq[q] = p;
    }
    // reduce over the 16-lane group sharing m (xor 1,2 via DPP; 4,8 via shfl)
    #pragma unroll
    for (int q = 0; q < 2; ++q){
      float v = qsum4(sq[q]);
      v += __shfl_xor(v, 4, 16);
      v += __shfl_xor(v, 8, 16);
      sq[q] = v;
    }
    if ((t2 & 15) == 0){
      sc[half][t2 >> 4]       = sq[0];
      sc[half][(t2 >> 4) + 8] = sq[1];
    }
  } else {
    // staged chunk ch covers m = ch>>5, d = (ch&31)*4 .. +4; thread's 4 chunks
    // (q=0..3) share d-range (t2&31)*4 and hit m = t2>>5 + 4q.
    float4 vra = *(const float4*)(vx + (t2 & 31) * 4);
    const float4* s = (const float4*)((const float*)xraw + (size_t)bt * 2048);
    float sq[4];
    #pragma unroll
    for (int q = 0; q < 4; ++q){
      int ch = t2 + 128 * q;
      float4 v = s[ch];
      *(float4*)&xdst[ch * 4] = v;
      float p = v.x * vra.x;
      p = fmaf(v.y, vra.y, p); p = fmaf(v.z, vra.z, p); p = fmaf(v.w, vra.w, p);
      sq[q] = p;
    }
    // reduce over the 32-lane group sharing m (xor 1,2 via DPP; 4,8,16 via shfl)
    #pragma unroll
    for (int q = 0; q < 4; ++q){
      float v = qsum4(sq[q]);
      v += __shfl_xor(v, 4, 32);
      v += __shfl_xor(v, 8, 32);
      v += __shfl_xor(v, 16, 32);
      sq[q] = v;
    }
    if ((t2 & 31) == 0){
      int mb = t2 >> 5;
      sc[half][mb]      = sq[0];
      sc[half][mb + 4]  = sq[1];
      sc[half][mb + 8]  = sq[2];
      sc[half][mb + 12] = sq[3];
    }
  }
  __syncthreads();

  float mx = sc[half][0];
  #pragma unroll
  for (int m2 = 1; m2 < MM; ++m2) mx = fmaxf(mx, sc[half][m2]);
  float wgt[MM]; float den = 0.f;
  #pragma unroll
  for (int m2 = 0; m2 < MM; ++m2){ wgt[m2] = __expf(sc[half][m2] - mx); den += wgt[m2]; }
  float inv = 1.0f / den;

  float acc = 0.f;
  #pragma unroll
  for (int m2 = 0; m2 < MM; ++m2)
    acc = fmaf(wgt[m2], xs[half][m2][t2], acc);   // addr%32 = t2%32: conflict-free
  newx[((size_t)t * BB + b) * DD + t2] = __float2half(acc * inv);
}

// ---------------- K2: MFMA x-projection -------------------------------------------
// Xp[r, G*128+j] = b_G[j] + sum_d newx[r,d] * W_G[d,j], as f16 MFMA GEMM.
// Per block: 128 rows x 128 cols, K=128. 4 waves, wave w owns rows w*32..w*32+32.
// A staged in LDS with 16B-granule XOR swizzle; B-frags pre-packed from Ww.
// C mapping col=lane&15, row=(lane>>4)*4+reg; A row map m=lane&15 (R4-verified).
__global__ __launch_bounds__(256) void k_xproj(const __half* __restrict__ nx,
  const uint4* __restrict__ Ww,
  const void* __restrict__ b0_, const void* __restrict__ b1_,
  const void* __restrict__ b2_, const void* __restrict__ b3_,
  const int* __restrict__ flag, float* __restrict__ Xp)
{
  __shared__ __align__(16) char As[32768];   // [128 rows][16 granules x 16B], swizzled
  int tid = threadIdx.x;
  int r0 = blockIdx.x * 128;
  int G  = blockIdx.y;
  int lane = tid & 63, w = tid >> 6;
  int l16 = lane & 15, lq = lane >> 4;

  // stage newx rows r0..r0+127 (256B rows), swizzled: granule c16 -> c16 ^ (r&15)
  {
    const uint4* src = (const uint4*)(nx + (size_t)r0 * DD);
    uint4* dst = (uint4*)As;
    #pragma unroll
    for (int i = 0; i < 8; ++i){
      int gid = i * 256 + tid;           // 0..2047
      int r = gid >> 4, c16 = gid & 15;
      dst[r * 16 + (c16 ^ (r & 15))] = src[gid];
    }
  }

  int mode = *flag;
  const void* bb = (G == 0) ? b0_ : (G == 1) ? b1_ : (G == 2) ? b2_ : b3_;
  float bias[8];
  #pragma unroll
  for (int cb = 0; cb < 8; ++cb){
    int col = cb * 16 + l16;
    bias[cb] = mode ? __uint_as_float(((uint)((const ushort*)bb)[col]) << 16)
                    : ((const float*)bb)[col];
  }
  __syncthreads();

  int rb = w * 32;                       // wave's row block
  f32x4 acc[2][8];
  #pragma unroll
  for (int mt = 0; mt < 2; ++mt)
    #pragma unroll
    for (int cb = 0; cb < 8; ++cb)
      acc[mt][cb] = (f32x4){bias[cb], bias[cb], bias[cb], bias[cb]};

  #pragma unroll
  for (int kc = 0; kc < 4; ++kc){
    f16x8 a[2];
    #pragma unroll
    for (int mt = 0; mt < 2; ++mt){
      int r = rb + mt * 16 + l16;
      int g16 = (kc * 4 + lq) ^ (r & 15);
      a[mt] = *(const f16x8*)(As + r * 256 + g16 * 16);
    }
    #pragma unroll
    for (int cb = 0; cb < 8; ++cb){
      union{uint4 u; f16x8 h;} bv;
      bv.u = Ww[((size_t)((G * 4 + kc) * 8 + cb)) * 64 + lane];
      acc[0][cb] = __builtin_amdgcn_mfma_f32_16x16x32_f16(a[0], bv.h, acc[0][cb], 0, 0, 0);
      acc[1][cb] = __builtin_amdgcn_mfma_f32_16x16x32_f16(a[1], bv.h, acc[1][cb], 0, 0, 0);
    }
  }

  #pragma unroll
  for (int mt = 0; mt < 2; ++mt)
    #pragma unroll
    for (int cb = 0; cb < 8; ++cb)
      #pragma unroll
      for (int reg = 0; reg < 4; ++reg){
        size_t r = (size_t)(r0 + rb + mt * 16 + lq * 4 + reg);
        Xp[r * 512 + G * HH + cb * 16 + l16] = acc[mt][cb][reg];
      }
}

// ---------------- K3: recurrence on the MATRIX pipe ---------------------------------
// R5 vs R4 (121.4us): accumulator-init trim. Only elem [0] of each f32x4 acc is
// ever read (A = h broadcast to all 16 rows -> all C rows identical), but the
// full-broadcast init cost 32 v_movs/wave/step (~25% of VALU issue). Now only
// elem 0 is initialized; elems 1-3 are undefined garbage that MFMA (elementwise
// over C) propagates into lanes we never read. 8 movs instead of 32.
__global__ __attribute__((amdgpu_waves_per_eu(2, 2))) __launch_bounds__(512)
void k_rec(const float* __restrict__ Xp, const uint4* __restrict__ Uw,
           float* __restrict__ out)
{
  __shared__ __align__(16) __half hlds[2][HH];   // 512 B double-buffered h
  int tid  = threadIdx.x;
  int b    = blockIdx.x;
  int w    = tid >> 6;          // wave id: col block w*16..w*16+15
  int lane = tid & 63;
  int l16  = lane & 15;

  // ---- B-frags: Ub[g*4+kc], 16 coalesced dwordx4 loads ----
  f16x8 Ub[16];
  #pragma unroll
  for (int g = 0; g < 4; ++g)
    #pragma unroll
    for (int kc = 0; kc < 4; ++kc){
      uint4 v = Uw[((g * 4 + kc) * 8 + w) * 64 + lane];
      union{uint4 u; f16x8 h;} cv; cv.u = v;
      Ub[g * 4 + kc] = cv.h;
    }

  // ---- per-thread Xp column pointer; prime t=0,1 ----
  const float* xcol = Xp + (size_t)b * 512 + w * 16 + l16;
  float xpA[4], xpB[4];
  #pragma unroll
  for (int g = 0; g < 4; ++g) xpA[g] = xcol[g * 128];
  #pragma unroll
  for (int g = 0; g < 4; ++g) xpB[g] = xcol[(size_t)(BB * 512) + g * 128];

  if (tid < 64) ((uint*)&hlds[0][0])[tid] = 0;   // h(0) = 0 (128 f16)
  float cst = 0.f, vh = 0.f;
  const int lo = (lane >> 4) * 16;               // byte offset of lane's k-slice
  __syncthreads();

#define STEP(T, XP) do{                                                        \
    const char* hb = (const char*)&hlds[(T) & 1][0];                           \
    f16x8 a0 = *(const f16x8*)(hb +   0 + lo);                                 \
    f16x8 a1 = *(const f16x8*)(hb +  64 + lo);                                 \
    f16x8 a2 = *(const f16x8*)(hb + 128 + lo);                                 \
    f16x8 a3 = *(const f16x8*)(hb + 192 + lo);                                 \
    f32x4 c0, c1, c2, c3, d0, d1, d2, d3;                                      \
    c0[0] = XP[0]; c1[0] = XP[1]; c2[0] = XP[2]; c3[0] = XP[3];                \
    d0[0] = 0.f;   d1[0] = 0.f;   d2[0] = 0.f;   d3[0] = 0.f;                  \
    c0 = __builtin_amdgcn_mfma_f32_16x16x32_f16(a0, Ub[ 0], c0, 0, 0, 0);      \
    c1 = __builtin_amdgcn_mfma_f32_16x16x32_f16(a0, Ub[ 4], c1, 0, 0, 0);      \
    c2 = __builtin_amdgcn_mfma_f32_16x16x32_f16(a0, Ub[ 8], c2, 0, 0, 0);      \
    c3 = __builtin_amdgcn_mfma_f32_16x16x32_f16(a0, Ub[12], c3, 0, 0, 0);      \
    d0 = __builtin_amdgcn_mfma_f32_16x16x32_f16(a2, Ub[ 2], d0, 0, 0, 0);      \
    d1 = __builtin_amdgcn_mfma_f32_16x16x32_f16(a2, Ub[ 6], d1, 0, 0, 0);      \
    d2 = __builtin_amdgcn_mfma_f32_16x16x32_f16(a2, Ub[10], d2, 0, 0, 0);      \
    d3 = __builtin_amdgcn_mfma_f32_16x16x32_f16(a2, Ub[14], d3, 0, 0, 0);      \
    c0 = __builtin_amdgcn_mfma_f32_16x16x32_f16(a1, Ub[ 1], c0, 0, 0, 0);      \
    c1 = __builtin_amdgcn_mfma_f32_16x16x32_f16(a1, Ub[ 5], c1, 0, 0, 0);      \
    c2 = __builtin_amdgcn_mfma_f32_16x16x32_f16(a1, Ub[ 9], c2, 0, 0, 0);      \
    c3 = __builtin_amdgcn_mfma_f32_16x16x32_f16(a1, Ub[13], c3, 0, 0, 0);      \
    d0 = __builtin_amdgcn_mfma_f32_16x16x32_f16(a3, Ub[ 3], d0, 0, 0, 0);      \
    d1 = __builtin_amdgcn_mfma_f32_16x16x32_f16(a3, Ub[ 7], d1, 0, 0, 0);      \
    d2 = __builtin_amdgcn_mfma_f32_16x16x32_f16(a3, Ub[11], d2, 0, 0, 0);      \
    d3 = __builtin_amdgcn_mfma_f32_16x16x32_f16(a3, Ub[15], d3, 0, 0, 0);      \
    float p0 = c0[0] + d0[0];                                                  \
    float p1 = c1[0] + d1[0];                                                  \
    float p2 = c2[0] + d2[0];                                                  \
    float p3 = c3[0] + d3[0];                                                  \
    float ig = hsig(p0), fg = hsig(p1), og = hsig(p3);                         \
    float gg = tanh_f(p2);                                                     \
    cst = fmaf(fg, cst, ig * gg);                                              \
    vh  = og * tanh_f(cst);                                                    \
    if (lane < 16) hlds[((T) + 1) & 1][w * 16 + lane] = __float2half(vh);      \
    {                                                                          \
      int tp = (T) + 2; if (tp > TT - 1) tp = TT - 1;                          \
      const float* xs = xcol + ((size_t)tp << 14);                             \
      _Pragma("unroll")                                                        \
      for (int g = 0; g < 4; ++g) XP[g] = xs[g * 128];                         \
    }                                                                          \
    asm volatile("s_waitcnt lgkmcnt(0)" ::: "memory");                         \
    __builtin_amdgcn_s_barrier();                                              \
    asm volatile("" ::: "memory");                                             \
  }while(0)

  for (int t = 0; t < TT; t += 2){
    STEP(t,     xpA);
    STEP(t + 1, xpB);
  }
#undef STEP

  if (lane < 16) out[b * HH + w * 16 + lane] = vh;
}

extern "C" void kernel_launch(void* const* d_in, const int* in_sizes, int n_in,
                              void* d_out, int out_size, void* d_ws, size_t ws_size,
                              hipStream_t stream) {
  (void)in_sizes; (void)n_in; (void)out_size; (void)ws_size;

  // ---- workspace layout (~18.4 MB) ----
  // [0,16)            flag
  // [16,528)          vx fp32[128]
  // [1024, +128KB)    Uw uint4[8192]  (MFMA B-fragments of U, f16)
  // [+, +128KB)       Ww uint4[8192]  (MFMA B-fragments of W, f16)
  // [+, +2MB)         newx f16[8192*128]
  // [+, +16MB)        Xp fp32[8192*512]
  char* ws = (char*)d_ws;
  int* flag = (int*)ws;
  float* vx = (float*)(ws + 16);
  uint4* Uw = (uint4*)(ws + 1024);
  uint4* Ww = (uint4*)(ws + 1024 + 131072);
  __half* newx = (__half*)(ws + 1024 + 2 * 131072);
  float* Xp = (float*)(ws + 1024 + 2 * 131072 + (size_t)2 * 1024 * 1024);

  k_prep<<<65, 256, 0, stream>>>(d_in[0], d_in[1],
      d_in[4], d_in[7], d_in[10], d_in[13],    // U_i, U_f, U_c, U_o
      d_in[3], d_in[6], d_in[9],  d_in[12],    // W_i, W_f, W_c, W_o
      flag, vx, Uw, Ww);
  k_pool<<<BB * TT / 2, 256, 0, stream>>>(d_in[0], flag, vx, newx);
  dim3 g2(64, 4);
  k_xproj<<<g2, 256, 0, stream>>>(newx, Ww,
      d_in[5], d_in[8], d_in[11], d_in[14],    // b_i, b_f, b_c, b_o
      flag, Xp);
  k_rec<<<BB, 512, 0, stream>>>(Xp, Uw, (float*)d_out);
}